// Round 10
// baseline (205.934 us; speedup 1.0000x reference)
//
#include <hip/hip_runtime.h>

#define DM    128
#define DI    256
#define NH    8
#define HD    32
#define NS    64
#define CDIM  384
#define DPROJ 648
#define LSEQ  4096
#define NB    8
#define NTOK  32768          // NB*LSEQ
#define LC    64             // chunk length
#define NC    64             // chunks per (b,h) sequence
#define EPSF  1e-5f
#define LOG2E 1.4426950408889634f

typedef __bf16 bf16;
typedef bf16  bf16x8 __attribute__((ext_vector_type(8)));
typedef bf16  bf16x4 __attribute__((ext_vector_type(4)));
typedef short short8 __attribute__((ext_vector_type(8)));
typedef float f32x4  __attribute__((ext_vector_type(4)));

__device__ __forceinline__ unsigned short f2bfbits(float f) {
    unsigned int u = __float_as_uint(f);
    unsigned int r = u + 0x7FFFu + ((u >> 16) & 1u);   // RNE
    return (unsigned short)(r >> 16);
}
__device__ __forceinline__ float bfbits2f(unsigned short u) {
    return __uint_as_float(((unsigned int)u) << 16);
}

// ---------------- 0. fp32 -> bf16 weight cast ----------------------------------
__global__ __launch_bounds__(256) void k_cast(const float* __restrict__ in,
                                              unsigned short* __restrict__ out, int n) {
    int i = blockIdx.x * 256 + threadIdx.x;
    if (i < n) out[i] = f2bfbits(in[i]);
}

// ---------------- 1. fused input RMSNorm + dt ----------------------------------
__global__ __launch_bounds__(256) void k_rmsdt(const float* __restrict__ x,
                                               const float* __restrict__ w,
                                               const float* __restrict__ w1,
                                               const float* __restrict__ dtb,
                                               unsigned short* __restrict__ xnb,
                                               float* __restrict__ dtf) {
    __shared__ float Xs[4][132];
    __shared__ float Wd[8][132];
    const int t = threadIdx.x;
    {
        int row = t >> 5, col = (t & 31) * 4;           // 8x128 = 256 float4
        *(float4*)&Wd[row][col] = *(const float4*)(w1 + (size_t)(640 + row) * DM + col);
    }
    const int wave = t >> 6, lane = t & 63;
    const size_t row = (size_t)blockIdx.x * 4 + wave;
    const float* xr = x + row * DM + lane * 2;
    float v0 = xr[0], v1 = xr[1];
    float ss = v0 * v0 + v1 * v1;
    #pragma unroll
    for (int o = 32; o; o >>= 1) ss += __shfl_xor(ss, o);
    float r = rsqrtf(ss * (1.0f / DM) + EPSF);
    float o0 = v0 * r * w[lane * 2], o1 = v1 * r * w[lane * 2 + 1];
    Xs[wave][lane * 2] = o0; Xs[wave][lane * 2 + 1] = o1;
    ushort2 ob; ob.x = f2bfbits(o0); ob.y = f2bfbits(o1);
    *(ushort2*)(xnb + row * DM + lane * 2) = ob;
    __syncthreads();
    const int h = lane >> 3, ks = lane & 7;
    float acc = 0.f;
    #pragma unroll
    for (int i = 0; i < 4; i++) {
        float4 xv = *(const float4*)&Xs[wave][ks * 16 + i * 4];
        float4 wv = *(const float4*)&Wd[h][ks * 16 + i * 4];
        acc = fmaf(xv.x, wv.x, acc);
        acc = fmaf(xv.y, wv.y, acc);
        acc = fmaf(xv.z, wv.z, acc);
        acc = fmaf(xv.w, wv.w, acc);
    }
    acc += __shfl_xor(acc, 1);
    acc += __shfl_xor(acc, 2);
    acc += __shfl_xor(acc, 4);
    if (ks == 0) {
        float v = acc + dtb[h];
        dtf[row * NH + h] = (v > 20.f) ? v : log1pf(expf(v));
    }
}

// ---------------- 2. GEMM1 (bf16 MFMA): split bf16 out (z | xBC) ---------------
__global__ __launch_bounds__(256) void k_gemm1(const unsigned short* __restrict__ A,
                                               const unsigned short* __restrict__ B,
                                               unsigned short* __restrict__ zb,
                                               unsigned short* __restrict__ xbc) {
    __shared__ bf16 As[64 * 40];
    __shared__ bf16 Bs[64 * 40];
    const int t = threadIdx.x;
    const int m0 = blockIdx.x * 64, n0 = blockIdx.y * 64;
    const int wave = t >> 6, lane = t & 63;
    const int wm = wave >> 1, wn = wave & 1;
    const int fr = lane & 15, fk = (lane >> 4) * 8;
    f32x4 acc[2][2] = {};
    const int r = t >> 2, q = (t & 3) * 8;
    for (int k0 = 0; k0 < DM; k0 += 32) {
        __syncthreads();
        *(short8*)&As[r * 40 + q] = *(const short8*)(A + (size_t)(m0 + r) * DM + k0 + q);
        short8 bv = {};
        if (n0 + r < DPROJ) bv = *(const short8*)(B + (size_t)(n0 + r) * DM + k0 + q);
        *(short8*)&Bs[r * 40 + q] = bv;
        __syncthreads();
        #pragma unroll
        for (int mt = 0; mt < 2; mt++) {
            bf16x8 af = *(const bf16x8*)&As[(wm * 32 + mt * 16 + fr) * 40 + fk];
            #pragma unroll
            for (int nt = 0; nt < 2; nt++) {
                bf16x8 bf = *(const bf16x8*)&Bs[(wn * 32 + nt * 16 + fr) * 40 + fk];
                acc[mt][nt] = __builtin_amdgcn_mfma_f32_16x16x32_bf16(af, bf, acc[mt][nt], 0, 0, 0);
            }
        }
    }
    #pragma unroll
    for (int mt = 0; mt < 2; mt++)
        #pragma unroll
        for (int nt = 0; nt < 2; nt++) {
            int n = n0 + wn * 32 + nt * 16 + fr;
            if (n >= 640) continue;
            #pragma unroll
            for (int rr = 0; rr < 4; rr++) {
                int m = m0 + wm * 32 + mt * 16 + (lane >> 4) * 4 + rr;
                unsigned short v = f2bfbits(acc[mt][nt][rr]);
                if (n < DI) zb[(size_t)m * DI + n] = v;
                else        xbc[(size_t)m * CDIM + (n - 256)] = v;
            }
        }
}

// ---------------- 3. causal depthwise conv (K=4) + SiLU, bf16 ------------------
__global__ __launch_bounds__(384) void k_conv(const unsigned short* __restrict__ xbc,
                                              const float* __restrict__ cw,
                                              const float* __restrict__ cb,
                                              unsigned short* __restrict__ xcb) {
    const int c = threadIdx.x;
    const int t0 = blockIdx.x * 64;
    const int l0 = t0 & (LSEQ - 1);
    float4 wv = *(const float4*)(cw + c * 4);
    float bias = cb[c];
    const unsigned short* in = xbc + (size_t)t0 * CDIM + c;
    unsigned short* out = xcb + (size_t)t0 * CDIM + c;
    float h1 = 0.f, h2 = 0.f, h3 = 0.f;
    if (l0) {
        h1 = bfbits2f(in[-CDIM]);
        h2 = bfbits2f(in[-2 * CDIM]);
        h3 = bfbits2f(in[-3 * CDIM]);
    }
    #pragma unroll 4
    for (int t = 0; t < 64; t++) {
        float x0 = bfbits2f(in[(size_t)t * CDIM]);
        float acc = bias;
        acc = fmaf(x0, wv.w, acc);
        acc = fmaf(h1, wv.z, acc);
        acc = fmaf(h2, wv.y, acc);
        acc = fmaf(h3, wv.x, acc);
        float s = acc / (1.f + expf(-acc));
        out[(size_t)t * CDIM] = f2bfbits(s);
        h3 = h2; h2 = h1; h1 = x0;
    }
}

// ---------------- 5a. SSD pass 1: chunk-local end state via MFMA, bf16 hst -----
__global__ __launch_bounds__(256, 2) void k_ssd1(const unsigned short* __restrict__ xcb,
                                                 const float* __restrict__ dtf,
                                                 const float* __restrict__ alog,
                                                 unsigned short* __restrict__ hst,
                                                 float* __restrict__ dAp) {
    __shared__ bf16 Wl[4][64 * 72];
    __shared__ bf16 Xl[4][64 * 40];
    __shared__ float wl[4][64];
    const int bh = blockIdx.x >> 4, cg = blockIdx.x & 15;
    const int b = bh >> 3, h = bh & 7;
    const int wave = threadIdx.x >> 6, lane = threadIdx.x & 63;
    const int c = cg * 4 + wave;
    const size_t tok0 = (size_t)b * LSEQ + c * LC;
    const float A = -expf(alog[h]);
    float dt = dtf[(tok0 + lane) * NH + h];
    float q = dt * A * LOG2E;
    #pragma unroll
    for (int o = 1; o <= 32; o <<= 1) {
        float tmp = __shfl_up(q, o);
        if (lane >= o) q += tmp;
    }
    float qL = __shfl(q, 63);
    wl[wave][lane] = exp2f(qL - q) * dt;
    const unsigned short* xrow = xcb + tok0 * CDIM;
    #pragma unroll
    for (int it = 0; it < 4; it++) {
        int f = it * 64 + lane, r = f >> 2, c8 = (f & 3) * 8;
        *(bf16x8*)&Xl[wave][r * 40 + c8] = *(const bf16x8*)(xrow + (size_t)r * CDIM + h * HD + c8);
    }
    #pragma unroll
    for (int it = 0; it < 8; it++) {
        int f = it * 64 + lane, r = f >> 3, c8 = (f & 7) * 8;
        float w = wl[wave][r];
        bf16x8 v = *(const bf16x8*)(xrow + (size_t)r * CDIM + 256 + c8);
        bf16x8 o;
        #pragma unroll
        for (int j = 0; j < 8; j++) o[j] = (bf16)((float)v[j] * w);
        *(bf16x8*)&Wl[wave][r * 72 + c8] = o;
    }
    const int m = lane & 15, ko = lane >> 4;
    f32x4 hacc[4][2] = {};
    #pragma unroll
    for (int kh = 0; kh < 2; kh++) {
        bf16x8 xb[2];
        #pragma unroll
        for (int pi = 0; pi < 2; pi++)
            #pragma unroll
            for (int j = 0; j < 8; j++)
                xb[pi][j] = Xl[wave][(kh * 32 + ko * 8 + j) * 40 + pi * 16 + m];
        #pragma unroll
        for (int ni = 0; ni < 4; ni++) {
            bf16x8 af;
            #pragma unroll
            for (int j = 0; j < 8; j++)
                af[j] = Wl[wave][(kh * 32 + ko * 8 + j) * 72 + ni * 16 + m];
            #pragma unroll
            for (int pi = 0; pi < 2; pi++)
                hacc[ni][pi] = __builtin_amdgcn_mfma_f32_16x16x32_bf16(af, xb[pi], hacc[ni][pi], 0, 0, 0);
        }
    }
    unsigned short* hb = hst + (((size_t)bh * NC + c) << 11);
    #pragma unroll
    for (int ni = 0; ni < 4; ni++)
        #pragma unroll
        for (int pi = 0; pi < 2; pi++)
            #pragma unroll
            for (int r = 0; r < 4; r++)
                hb[(ni * 16 + ko * 4 + r) * 32 + pi * 16 + m] = f2bfbits(hacc[ni][pi][r]);
    if (lane == 0) dAp[(size_t)bh * NC + c] = exp2f(qL);
}

// ---------------- 5b. SSM pass 2: scan over bf16 chunk states ------------------
__global__ __launch_bounds__(256) void k_ssm2(unsigned short* __restrict__ hst,
                                              const float* __restrict__ dAp) {
    __shared__ float dl[2][NC];
    const int pr = blockIdx.x >> 3, seg = blockIdx.x & 7;
    const int bh0 = pr * 2, bh1 = pr * 2 + 1;
    const int s = seg * 256 + threadIdx.x;
    if (threadIdx.x < NC) dl[0][threadIdx.x] = dAp[(size_t)bh0 * NC + threadIdx.x];
    else if (threadIdx.x < 2 * NC) dl[1][threadIdx.x - NC] = dAp[(size_t)bh1 * NC + threadIdx.x - NC];
    __syncthreads();
    unsigned short* b0 = hst + ((size_t)bh0 * NC << 11) + s;
    unsigned short* b1 = hst + ((size_t)bh1 * NC << 11) + s;
    float r0 = 0.f, r1 = 0.f;
    float n0 = bfbits2f(b0[0]), n1 = bfbits2f(b1[0]);
    for (int c = 0; c < NC; c++) {
        float t0 = n0, t1 = n1;
        if (c + 1 < NC) {
            n0 = bfbits2f(b0[(size_t)(c + 1) << 11]);
            n1 = bfbits2f(b1[(size_t)(c + 1) << 11]);
        }
        b0[(size_t)c << 11] = f2bfbits(r0);
        b1[(size_t)c << 11] = f2bfbits(r1);
        r0 = fmaf(r0, dl[0][c], t0);
        r1 = fmaf(r1, dl[1][c], t1);
    }
}

// ---------------- 5c. SSD pass 3: Y = P.X + diag(2^q).(C.h_in^T), bf16 out -----
__global__ __launch_bounds__(256, 2) void k_ssd3(const unsigned short* __restrict__ xcb,
                                                 const float* __restrict__ dtf,
                                                 const float* __restrict__ alog,
                                                 const unsigned short* __restrict__ hst,
                                                 const float* __restrict__ Dw,
                                                 unsigned short* __restrict__ ybb) {
    __shared__ bf16 Pl[4][64 * 72];
    __shared__ bf16 Xl[4][64 * 40];
    __shared__ bf16 Hl[4][64 * 40];
    __shared__ float ql[4][64];
    __shared__ float dl[4][64];
    const int bh = blockIdx.x >> 4, cg = blockIdx.x & 15;
    const int b = bh >> 3, h = bh & 7;
    const int wave = threadIdx.x >> 6, lane = threadIdx.x & 63;
    const int c = cg * 4 + wave;
    const size_t tok0 = (size_t)b * LSEQ + c * LC;
    const float A = -expf(alog[h]);
    const float Dh = Dw[h];
    float dt = dtf[(tok0 + lane) * NH + h];
    float q = dt * A * LOG2E;
    #pragma unroll
    for (int o = 1; o <= 32; o <<= 1) {
        float tmp = __shfl_up(q, o);
        if (lane >= o) q += tmp;
    }
    ql[wave][lane] = q;
    dl[wave][lane] = dt;
    const unsigned short* xrow = xcb + tok0 * CDIM;
    #pragma unroll
    for (int it = 0; it < 4; it++) {
        int f = it * 64 + lane, r = f >> 2, c8 = (f & 3) * 8;
        *(bf16x8*)&Xl[wave][r * 40 + c8] = *(const bf16x8*)(xrow + (size_t)r * CDIM + h * HD + c8);
    }
    const unsigned short* hbg = hst + (((size_t)bh * NC + c) << 11);
    #pragma unroll
    for (int it = 0; it < 4; it++) {
        int f = it * 64 + lane, n = f >> 2, p8 = (f & 3) * 8;
        *(bf16x8*)&Hl[wave][n * 40 + p8] = *(const bf16x8*)(hbg + f * 8);
    }
    const int m = lane & 15, ko = lane >> 4;
    bf16x8 cf[4][2];
    #pragma unroll
    for (int ti = 0; ti < 4; ti++)
        #pragma unroll
        for (int kh = 0; kh < 2; kh++)
            cf[ti][kh] = *(const bf16x8*)(xrow + (size_t)(ti * 16 + m) * CDIM + 320 + kh * 32 + ko * 8);
    f32x4 g[4][4] = {};
    #pragma unroll
    for (int kh = 0; kh < 2; kh++) {
        bf16x8 bfg[4];
        #pragma unroll
        for (int si = 0; si < 4; si++)
            bfg[si] = *(const bf16x8*)(xrow + (size_t)(si * 16 + m) * CDIM + 256 + kh * 32 + ko * 8);
        #pragma unroll
        for (int ti = 0; ti < 4; ti++)
            #pragma unroll
            for (int si = 0; si < 4; si++)
                g[ti][si] = __builtin_amdgcn_mfma_f32_16x16x32_bf16(cf[ti][kh], bfg[si], g[ti][si], 0, 0, 0);
    }
    __syncthreads();
    float qt[4][4], et[4][4];
    #pragma unroll
    for (int ti = 0; ti < 4; ti++)
        #pragma unroll
        for (int r = 0; r < 4; r++) {
            float v = ql[wave][ti * 16 + ko * 4 + r];
            qt[ti][r] = v; et[ti][r] = exp2f(v);
        }
    float qs[4], ds[4];
    #pragma unroll
    for (int si = 0; si < 4; si++) {
        qs[si] = ql[wave][si * 16 + m];
        ds[si] = dl[wave][si * 16 + m];
    }
    #pragma unroll
    for (int ti = 0; ti < 4; ti++)
        #pragma unroll
        for (int si = 0; si < 4; si++)
            #pragma unroll
            for (int r = 0; r < 4; r++) {
                int t = ti * 16 + ko * 4 + r, s = si * 16 + m;
                float p = 0.f;
                if (si <= ti) {
                    float w = (s <= t) ? exp2f(qt[ti][r] - qs[si]) * ds[si] : 0.f;
                    p = g[ti][si][r] * w;
                    if (s == t) p += Dh;
                }
                Pl[wave][t * 72 + s] = (bf16)p;
            }
    f32x4 ya[4][2] = {}, ua[4][2] = {};
    #pragma unroll
    for (int kh = 0; kh < 2; kh++) {
        bf16x8 xb[2], hb2[2];
        #pragma unroll
        for (int pi = 0; pi < 2; pi++)
            #pragma unroll
            for (int j = 0; j < 8; j++) {
                int kk = kh * 32 + ko * 8 + j;
                xb[pi][j]  = Xl[wave][kk * 40 + pi * 16 + m];
                hb2[pi][j] = Hl[wave][kk * 40 + pi * 16 + m];
            }
        #pragma unroll
        for (int ti = 0; ti < 4; ti++) {
            bf16x8 pa = *(const bf16x8*)&Pl[wave][(ti * 16 + m) * 72 + kh * 32 + ko * 8];
            #pragma unroll
            for (int pi = 0; pi < 2; pi++) {
                ya[ti][pi] = __builtin_amdgcn_mfma_f32_16x16x32_bf16(pa, xb[pi], ya[ti][pi], 0, 0, 0);
                ua[ti][pi] = __builtin_amdgcn_mfma_f32_16x16x32_bf16(cf[ti][kh], hb2[pi], ua[ti][pi], 0, 0, 0);
            }
        }
    }
    unsigned short* yrow = ybb + tok0 * DI + h * HD;
    #pragma unroll
    for (int ti = 0; ti < 4; ti++)
        #pragma unroll
        for (int pi = 0; pi < 2; pi++)
            #pragma unroll
            for (int r = 0; r < 4; r++) {
                int t = ti * 16 + ko * 4 + r;
                yrow[(size_t)t * DI + pi * 16 + m] =
                    f2bfbits(ya[ti][pi][r] + et[ti][r] * ua[ti][pi][r]);
            }
}

// ---------------- 6+7. fused gate + GEMM2 + residual (register A-frags) --------
// wave w owns rows m0+w*16..+15; thread (fr=lane&15, ko=lane>>4) gates row fr's
// cols {ko*8 + kk*32} — exactly its MFMA A-fragments. Row sum-sq closes with 2
// shuffles across the 4 ko-lanes. B-frags load direct from L2-resident W2.
__global__ __launch_bounds__(256, 4) void k_gemm2g(const unsigned short* __restrict__ ybb,
                                                   const unsigned short* __restrict__ zb,
                                                   const float* __restrict__ gw,
                                                   const unsigned short* __restrict__ w2b,
                                                   const float* __restrict__ xin,
                                                   float* __restrict__ out) {
    __shared__ float gwl[256];
    const int t = threadIdx.x;
    gwl[t] = gw[t];
    const int wave = t >> 6, lane = t & 63;
    const int fr = lane & 15, ko = lane >> 4;
    const int m0 = blockIdx.x * 64 + wave * 16;
    const size_t rowo = (size_t)(m0 + fr) * DI;
    float ss = 0.f;
    bf16x8 gb[8];
    #pragma unroll
    for (int kk = 0; kk < 8; kk++) {
        int co = kk * 32 + ko * 8;
        bf16x8 yv = *(const bf16x8*)(ybb + rowo + co);
        bf16x8 zv = *(const bf16x8*)(zb + rowo + co);
        #pragma unroll
        for (int j = 0; j < 8; j++) {
            float z = (float)zv[j];
            float g = (float)yv[j] * (z / (1.f + expf(-z)));
            ss += g * g;
            gb[kk][j] = (bf16)g;
        }
    }
    ss += __shfl_xor(ss, 16);
    ss += __shfl_xor(ss, 32);
    const float rs = rsqrtf(ss * (1.0f / DI) + EPSF);
    __syncthreads();
    #pragma unroll
    for (int kk = 0; kk < 8; kk++) {
        int co = kk * 32 + ko * 8;
        #pragma unroll
        for (int j = 0; j < 8; j++)
            gb[kk][j] = (bf16)((float)gb[kk][j] * rs * gwl[co + j]);
    }
    f32x4 acc[8] = {};
    #pragma unroll
    for (int kk = 0; kk < 8; kk++) {
        #pragma unroll
        for (int nt = 0; nt < 8; nt++) {
            bf16x8 bfr = *(const bf16x8*)(w2b + (size_t)(nt * 16 + fr) * DI + kk * 32 + ko * 8);
            acc[nt] = __builtin_amdgcn_mfma_f32_16x16x32_bf16(gb[kk], bfr, acc[nt], 0, 0, 0);
        }
    }
    #pragma unroll
    for (int nt = 0; nt < 8; nt++) {
        int n = nt * 16 + fr;
        #pragma unroll
        for (int rr = 0; rr < 4; rr++) {
            int m = m0 + ko * 4 + rr;
            out[(size_t)m * DM + n] = xin[(size_t)m * DM + n] + acc[nt][rr];
        }
    }
}

extern "C" void kernel_launch(void* const* d_in, const int* in_sizes, int n_in,
                              void* d_out, int out_size, void* d_ws, size_t ws_size,
                              hipStream_t stream) {
    const float* x   = (const float*)d_in[0];
    const float* nw  = (const float*)d_in[1];
    const float* w1  = (const float*)d_in[2];
    const float* cw  = (const float*)d_in[3];
    const float* cb  = (const float*)d_in[4];
    const float* dtb = (const float*)d_in[5];
    const float* al  = (const float*)d_in[6];
    const float* Dw  = (const float*)d_in[7];
    const float* gw  = (const float*)d_in[8];
    const float* w2  = (const float*)d_in[9];
    float* out = (float*)d_out;

    float* ws = (float*)d_ws;
    float*  dAp = ws;                                   // 4096 fp32
    float*  dtf = dAp + NB * NH * NC;                   // NTOK*8 fp32
    unsigned short* hst = (unsigned short*)(dtf + (size_t)NTOK * NH); // 64*64*2048 bf16
    unsigned short* zb  = hst + (size_t)NB * NH * NC * 2048;          // NTOK*256 bf16
    unsigned short* xbc = zb + (size_t)NTOK * DI;                     // NTOK*384 bf16
    unsigned short* xcb = xbc + (size_t)NTOK * CDIM;                  // NTOK*384 bf16
    unsigned short* ybb = xcb + (size_t)NTOK * CDIM;                  // NTOK*256 bf16
    unsigned short* w1b = ybb + (size_t)NTOK * DI;                    // 648*128
    unsigned short* w2b = w1b + (size_t)DPROJ * DM;                   // 128*256
    // alias (lifetimes disjoint): xnb dead before ssd3 writes ybb
    unsigned short* xnb = ybb;

    k_cast<<<(DPROJ * DM + 255) / 256, 256, 0, stream>>>(w1, w1b, DPROJ * DM);
    k_cast<<<(DM * DI + 255) / 256, 256, 0, stream>>>(w2, w2b, DM * DI);
    k_rmsdt<<<NTOK / 4, 256, 0, stream>>>(x, nw, w1, dtb, xnb, dtf);
    k_gemm1<<<dim3(NTOK / 64, (DPROJ + 63) / 64), 256, 0, stream>>>(xnb, w1b, zb, xbc);
    k_conv<<<NTOK / 64, 384, 0, stream>>>(xbc, cw, cb, xcb);
    k_ssd1<<<NB * NH * (NC / 4), 256, 0, stream>>>(xcb, dtf, al, hst, dAp);
    k_ssm2<<<(NB * NH / 2) * 8, 256, 0, stream>>>(hst, dAp);
    k_ssd3<<<NB * NH * (NC / 4), 256, 0, stream>>>(xcb, dtf, al, hst, Dw, ybb);
    k_gemm2g<<<NTOK / 64, 256, 0, stream>>>(ybb, zb, gw, w2b, x, out);
}

// Round 11
// 193.890 us; speedup vs baseline: 1.0621x; 1.0621x over previous
//
#include <hip/hip_runtime.h>

#define DM    128
#define DI    256
#define NH    8
#define HD    32
#define NS    64
#define CDIM  384
#define DPROJ 648
#define LSEQ  4096
#define NB    8
#define NTOK  32768          // NB*LSEQ
#define LC    64             // chunk length
#define NC    64             // chunks per (b,h) sequence
#define EPSF  1e-5f
#define LOG2E 1.4426950408889634f

typedef __bf16 bf16;
typedef bf16  bf16x8 __attribute__((ext_vector_type(8)));
typedef bf16  bf16x4 __attribute__((ext_vector_type(4)));
typedef short short8 __attribute__((ext_vector_type(8)));
typedef float f32x4  __attribute__((ext_vector_type(4)));

__device__ __forceinline__ unsigned short f2bfbits(float f) {
    unsigned int u = __float_as_uint(f);
    unsigned int r = u + 0x7FFFu + ((u >> 16) & 1u);   // RNE
    return (unsigned short)(r >> 16);
}
__device__ __forceinline__ float bfbits2f(unsigned short u) {
    return __uint_as_float(((unsigned int)u) << 16);
}

// ---------------- 0. fp32 -> bf16 weight cast ----------------------------------
__global__ __launch_bounds__(256) void k_cast(const float* __restrict__ in,
                                              unsigned short* __restrict__ out, int n) {
    int i = blockIdx.x * 256 + threadIdx.x;
    if (i < n) out[i] = f2bfbits(in[i]);
}

// ---------------- 1. fused input RMSNorm + dt ----------------------------------
__global__ __launch_bounds__(256) void k_rmsdt(const float* __restrict__ x,
                                               const float* __restrict__ w,
                                               const float* __restrict__ w1,
                                               const float* __restrict__ dtb,
                                               unsigned short* __restrict__ xnb,
                                               float* __restrict__ dtf) {
    __shared__ float Xs[4][132];
    __shared__ float Wd[8][132];
    const int t = threadIdx.x;
    {
        int row = t >> 5, col = (t & 31) * 4;           // 8x128 = 256 float4
        *(float4*)&Wd[row][col] = *(const float4*)(w1 + (size_t)(640 + row) * DM + col);
    }
    const int wave = t >> 6, lane = t & 63;
    const size_t row = (size_t)blockIdx.x * 4 + wave;
    const float* xr = x + row * DM + lane * 2;
    float v0 = xr[0], v1 = xr[1];
    float ss = v0 * v0 + v1 * v1;
    #pragma unroll
    for (int o = 32; o; o >>= 1) ss += __shfl_xor(ss, o);
    float r = rsqrtf(ss * (1.0f / DM) + EPSF);
    float o0 = v0 * r * w[lane * 2], o1 = v1 * r * w[lane * 2 + 1];
    Xs[wave][lane * 2] = o0; Xs[wave][lane * 2 + 1] = o1;
    ushort2 ob; ob.x = f2bfbits(o0); ob.y = f2bfbits(o1);
    *(ushort2*)(xnb + row * DM + lane * 2) = ob;
    __syncthreads();
    const int h = lane >> 3, ks = lane & 7;
    float acc = 0.f;
    #pragma unroll
    for (int i = 0; i < 4; i++) {
        float4 xv = *(const float4*)&Xs[wave][ks * 16 + i * 4];
        float4 wv = *(const float4*)&Wd[h][ks * 16 + i * 4];
        acc = fmaf(xv.x, wv.x, acc);
        acc = fmaf(xv.y, wv.y, acc);
        acc = fmaf(xv.z, wv.z, acc);
        acc = fmaf(xv.w, wv.w, acc);
    }
    acc += __shfl_xor(acc, 1);
    acc += __shfl_xor(acc, 2);
    acc += __shfl_xor(acc, 4);
    if (ks == 0) {
        float v = acc + dtb[h];
        dtf[row * NH + h] = (v > 20.f) ? v : log1pf(expf(v));
    }
}

// ---------------- 2. GEMM1 (bf16 MFMA): split bf16 out (z | xBC) ---------------
__global__ __launch_bounds__(256) void k_gemm1(const unsigned short* __restrict__ A,
                                               const unsigned short* __restrict__ B,
                                               unsigned short* __restrict__ zb,
                                               unsigned short* __restrict__ xbc) {
    __shared__ bf16 As[64 * 40];
    __shared__ bf16 Bs[64 * 40];
    const int t = threadIdx.x;
    const int m0 = blockIdx.x * 64, n0 = blockIdx.y * 64;
    const int wave = t >> 6, lane = t & 63;
    const int wm = wave >> 1, wn = wave & 1;
    const int fr = lane & 15, fk = (lane >> 4) * 8;
    f32x4 acc[2][2] = {};
    const int r = t >> 2, q = (t & 3) * 8;
    for (int k0 = 0; k0 < DM; k0 += 32) {
        __syncthreads();
        *(short8*)&As[r * 40 + q] = *(const short8*)(A + (size_t)(m0 + r) * DM + k0 + q);
        short8 bv = {};
        if (n0 + r < DPROJ) bv = *(const short8*)(B + (size_t)(n0 + r) * DM + k0 + q);
        *(short8*)&Bs[r * 40 + q] = bv;
        __syncthreads();
        #pragma unroll
        for (int mt = 0; mt < 2; mt++) {
            bf16x8 af = *(const bf16x8*)&As[(wm * 32 + mt * 16 + fr) * 40 + fk];
            #pragma unroll
            for (int nt = 0; nt < 2; nt++) {
                bf16x8 bf = *(const bf16x8*)&Bs[(wn * 32 + nt * 16 + fr) * 40 + fk];
                acc[mt][nt] = __builtin_amdgcn_mfma_f32_16x16x32_bf16(af, bf, acc[mt][nt], 0, 0, 0);
            }
        }
    }
    #pragma unroll
    for (int mt = 0; mt < 2; mt++)
        #pragma unroll
        for (int nt = 0; nt < 2; nt++) {
            int n = n0 + wn * 32 + nt * 16 + fr;
            if (n >= 640) continue;
            #pragma unroll
            for (int rr = 0; rr < 4; rr++) {
                int m = m0 + wm * 32 + mt * 16 + (lane >> 4) * 4 + rr;
                unsigned short v = f2bfbits(acc[mt][nt][rr]);
                if (n < DI) zb[(size_t)m * DI + n] = v;
                else        xbc[(size_t)m * CDIM + (n - 256)] = v;
            }
        }
}

// ---------------- 3. causal depthwise conv (K=4) + SiLU, bf16 ------------------
__global__ __launch_bounds__(384) void k_conv(const unsigned short* __restrict__ xbc,
                                              const float* __restrict__ cw,
                                              const float* __restrict__ cb,
                                              unsigned short* __restrict__ xcb) {
    const int c = threadIdx.x;
    const int t0 = blockIdx.x * 64;
    const int l0 = t0 & (LSEQ - 1);
    float4 wv = *(const float4*)(cw + c * 4);
    float bias = cb[c];
    const unsigned short* in = xbc + (size_t)t0 * CDIM + c;
    unsigned short* out = xcb + (size_t)t0 * CDIM + c;
    float h1 = 0.f, h2 = 0.f, h3 = 0.f;
    if (l0) {
        h1 = bfbits2f(in[-CDIM]);
        h2 = bfbits2f(in[-2 * CDIM]);
        h3 = bfbits2f(in[-3 * CDIM]);
    }
    #pragma unroll 4
    for (int t = 0; t < 64; t++) {
        float x0 = bfbits2f(in[(size_t)t * CDIM]);
        float acc = bias;
        acc = fmaf(x0, wv.w, acc);
        acc = fmaf(h1, wv.z, acc);
        acc = fmaf(h2, wv.y, acc);
        acc = fmaf(h3, wv.x, acc);
        float s = acc / (1.f + expf(-acc));
        out[(size_t)t * CDIM] = f2bfbits(s);
        h3 = h2; h2 = h1; h1 = x0;
    }
}

// ---------------- 5a. SSD pass 1: chunk-local end state via MFMA, bf16 hst -----
__global__ __launch_bounds__(256, 2) void k_ssd1(const unsigned short* __restrict__ xcb,
                                                 const float* __restrict__ dtf,
                                                 const float* __restrict__ alog,
                                                 unsigned short* __restrict__ hst,
                                                 float* __restrict__ dAp) {
    __shared__ bf16 Wl[4][64 * 72];
    __shared__ bf16 Xl[4][64 * 40];
    __shared__ float wl[4][64];
    const int bh = blockIdx.x >> 4, cg = blockIdx.x & 15;
    const int b = bh >> 3, h = bh & 7;
    const int wave = threadIdx.x >> 6, lane = threadIdx.x & 63;
    const int c = cg * 4 + wave;
    const size_t tok0 = (size_t)b * LSEQ + c * LC;
    const float A = -expf(alog[h]);
    float dt = dtf[(tok0 + lane) * NH + h];
    float q = dt * A * LOG2E;
    #pragma unroll
    for (int o = 1; o <= 32; o <<= 1) {
        float tmp = __shfl_up(q, o);
        if (lane >= o) q += tmp;
    }
    float qL = __shfl(q, 63);
    wl[wave][lane] = exp2f(qL - q) * dt;
    const unsigned short* xrow = xcb + tok0 * CDIM;
    #pragma unroll
    for (int it = 0; it < 4; it++) {
        int f = it * 64 + lane, r = f >> 2, c8 = (f & 3) * 8;
        *(bf16x8*)&Xl[wave][r * 40 + c8] = *(const bf16x8*)(xrow + (size_t)r * CDIM + h * HD + c8);
    }
    #pragma unroll
    for (int it = 0; it < 8; it++) {
        int f = it * 64 + lane, r = f >> 3, c8 = (f & 7) * 8;
        float w = wl[wave][r];
        bf16x8 v = *(const bf16x8*)(xrow + (size_t)r * CDIM + 256 + c8);
        bf16x8 o;
        #pragma unroll
        for (int j = 0; j < 8; j++) o[j] = (bf16)((float)v[j] * w);
        *(bf16x8*)&Wl[wave][r * 72 + c8] = o;
    }
    const int m = lane & 15, ko = lane >> 4;
    f32x4 hacc[4][2] = {};
    #pragma unroll
    for (int kh = 0; kh < 2; kh++) {
        bf16x8 xb[2];
        #pragma unroll
        for (int pi = 0; pi < 2; pi++)
            #pragma unroll
            for (int j = 0; j < 8; j++)
                xb[pi][j] = Xl[wave][(kh * 32 + ko * 8 + j) * 40 + pi * 16 + m];
        #pragma unroll
        for (int ni = 0; ni < 4; ni++) {
            bf16x8 af;
            #pragma unroll
            for (int j = 0; j < 8; j++)
                af[j] = Wl[wave][(kh * 32 + ko * 8 + j) * 72 + ni * 16 + m];
            #pragma unroll
            for (int pi = 0; pi < 2; pi++)
                hacc[ni][pi] = __builtin_amdgcn_mfma_f32_16x16x32_bf16(af, xb[pi], hacc[ni][pi], 0, 0, 0);
        }
    }
    unsigned short* hb = hst + (((size_t)bh * NC + c) << 11);
    #pragma unroll
    for (int ni = 0; ni < 4; ni++)
        #pragma unroll
        for (int pi = 0; pi < 2; pi++)
            #pragma unroll
            for (int r = 0; r < 4; r++)
                hb[(ni * 16 + ko * 4 + r) * 32 + pi * 16 + m] = f2bfbits(hacc[ni][pi][r]);
    if (lane == 0) dAp[(size_t)bh * NC + c] = exp2f(qL);
}

// ---------------- 5b. SSM pass 2: scan over bf16 chunk states ------------------
__global__ __launch_bounds__(256) void k_ssm2(unsigned short* __restrict__ hst,
                                              const float* __restrict__ dAp) {
    __shared__ float dl[2][NC];
    const int pr = blockIdx.x >> 3, seg = blockIdx.x & 7;
    const int bh0 = pr * 2, bh1 = pr * 2 + 1;
    const int s = seg * 256 + threadIdx.x;
    if (threadIdx.x < NC) dl[0][threadIdx.x] = dAp[(size_t)bh0 * NC + threadIdx.x];
    else if (threadIdx.x < 2 * NC) dl[1][threadIdx.x - NC] = dAp[(size_t)bh1 * NC + threadIdx.x - NC];
    __syncthreads();
    unsigned short* b0 = hst + ((size_t)bh0 * NC << 11) + s;
    unsigned short* b1 = hst + ((size_t)bh1 * NC << 11) + s;
    float r0 = 0.f, r1 = 0.f;
    float n0 = bfbits2f(b0[0]), n1 = bfbits2f(b1[0]);
    for (int c = 0; c < NC; c++) {
        float t0 = n0, t1 = n1;
        if (c + 1 < NC) {
            n0 = bfbits2f(b0[(size_t)(c + 1) << 11]);
            n1 = bfbits2f(b1[(size_t)(c + 1) << 11]);
        }
        b0[(size_t)c << 11] = f2bfbits(r0);
        b1[(size_t)c << 11] = f2bfbits(r1);
        r0 = fmaf(r0, dl[0][c], t0);
        r1 = fmaf(r1, dl[1][c], t1);
    }
}

// ---------------- 5c. SSD pass 3: Y = P.X + diag(2^q).(C.h_in^T), bf16 out -----
__global__ __launch_bounds__(256, 2) void k_ssd3(const unsigned short* __restrict__ xcb,
                                                 const float* __restrict__ dtf,
                                                 const float* __restrict__ alog,
                                                 const unsigned short* __restrict__ hst,
                                                 const float* __restrict__ Dw,
                                                 unsigned short* __restrict__ ybb) {
    __shared__ bf16 Pl[4][64 * 72];
    __shared__ bf16 Xl[4][64 * 40];
    __shared__ bf16 Hl[4][64 * 40];
    __shared__ float ql[4][64];
    __shared__ float dl[4][64];
    const int bh = blockIdx.x >> 4, cg = blockIdx.x & 15;
    const int b = bh >> 3, h = bh & 7;
    const int wave = threadIdx.x >> 6, lane = threadIdx.x & 63;
    const int c = cg * 4 + wave;
    const size_t tok0 = (size_t)b * LSEQ + c * LC;
    const float A = -expf(alog[h]);
    const float Dh = Dw[h];
    float dt = dtf[(tok0 + lane) * NH + h];
    float q = dt * A * LOG2E;
    #pragma unroll
    for (int o = 1; o <= 32; o <<= 1) {
        float tmp = __shfl_up(q, o);
        if (lane >= o) q += tmp;
    }
    ql[wave][lane] = q;
    dl[wave][lane] = dt;
    const unsigned short* xrow = xcb + tok0 * CDIM;
    #pragma unroll
    for (int it = 0; it < 4; it++) {
        int f = it * 64 + lane, r = f >> 2, c8 = (f & 3) * 8;
        *(bf16x8*)&Xl[wave][r * 40 + c8] = *(const bf16x8*)(xrow + (size_t)r * CDIM + h * HD + c8);
    }
    const unsigned short* hbg = hst + (((size_t)bh * NC + c) << 11);
    #pragma unroll
    for (int it = 0; it < 4; it++) {
        int f = it * 64 + lane, n = f >> 2, p8 = (f & 3) * 8;
        *(bf16x8*)&Hl[wave][n * 40 + p8] = *(const bf16x8*)(hbg + f * 8);
    }
    const int m = lane & 15, ko = lane >> 4;
    bf16x8 cf[4][2];
    #pragma unroll
    for (int ti = 0; ti < 4; ti++)
        #pragma unroll
        for (int kh = 0; kh < 2; kh++)
            cf[ti][kh] = *(const bf16x8*)(xrow + (size_t)(ti * 16 + m) * CDIM + 320 + kh * 32 + ko * 8);
    f32x4 g[4][4] = {};
    #pragma unroll
    for (int kh = 0; kh < 2; kh++) {
        bf16x8 bfg[4];
        #pragma unroll
        for (int si = 0; si < 4; si++)
            bfg[si] = *(const bf16x8*)(xrow + (size_t)(si * 16 + m) * CDIM + 256 + kh * 32 + ko * 8);
        #pragma unroll
        for (int ti = 0; ti < 4; ti++)
            #pragma unroll
            for (int si = 0; si < 4; si++)
                g[ti][si] = __builtin_amdgcn_mfma_f32_16x16x32_bf16(cf[ti][kh], bfg[si], g[ti][si], 0, 0, 0);
    }
    __syncthreads();
    float qt[4][4], et[4][4];
    #pragma unroll
    for (int ti = 0; ti < 4; ti++)
        #pragma unroll
        for (int r = 0; r < 4; r++) {
            float v = ql[wave][ti * 16 + ko * 4 + r];
            qt[ti][r] = v; et[ti][r] = exp2f(v);
        }
    float qs[4], ds[4];
    #pragma unroll
    for (int si = 0; si < 4; si++) {
        qs[si] = ql[wave][si * 16 + m];
        ds[si] = dl[wave][si * 16 + m];
    }
    #pragma unroll
    for (int ti = 0; ti < 4; ti++)
        #pragma unroll
        for (int si = 0; si < 4; si++)
            #pragma unroll
            for (int r = 0; r < 4; r++) {
                int t = ti * 16 + ko * 4 + r, s = si * 16 + m;
                float p = 0.f;
                if (si <= ti) {
                    float w = (s <= t) ? exp2f(qt[ti][r] - qs[si]) * ds[si] : 0.f;
                    p = g[ti][si][r] * w;
                    if (s == t) p += Dh;
                }
                Pl[wave][t * 72 + s] = (bf16)p;
            }
    f32x4 ya[4][2] = {}, ua[4][2] = {};
    #pragma unroll
    for (int kh = 0; kh < 2; kh++) {
        bf16x8 xb[2], hb2[2];
        #pragma unroll
        for (int pi = 0; pi < 2; pi++)
            #pragma unroll
            for (int j = 0; j < 8; j++) {
                int kk = kh * 32 + ko * 8 + j;
                xb[pi][j]  = Xl[wave][kk * 40 + pi * 16 + m];
                hb2[pi][j] = Hl[wave][kk * 40 + pi * 16 + m];
            }
        #pragma unroll
        for (int ti = 0; ti < 4; ti++) {
            bf16x8 pa = *(const bf16x8*)&Pl[wave][(ti * 16 + m) * 72 + kh * 32 + ko * 8];
            #pragma unroll
            for (int pi = 0; pi < 2; pi++) {
                ya[ti][pi] = __builtin_amdgcn_mfma_f32_16x16x32_bf16(pa, xb[pi], ya[ti][pi], 0, 0, 0);
                ua[ti][pi] = __builtin_amdgcn_mfma_f32_16x16x32_bf16(cf[ti][kh], hb2[pi], ua[ti][pi], 0, 0, 0);
            }
        }
    }
    unsigned short* yrow = ybb + tok0 * DI + h * HD;
    #pragma unroll
    for (int ti = 0; ti < 4; ti++)
        #pragma unroll
        for (int pi = 0; pi < 2; pi++)
            #pragma unroll
            for (int r = 0; r < 4; r++) {
                int t = ti * 16 + ko * 4 + r;
                yrow[(size_t)t * DI + pi * 16 + m] =
                    f2bfbits(ya[ti][pi][r] + et[ti][r] * ua[ti][pi][r]);
            }
}

// ---------------- 6+7. fused gate + GEMM2 + residual (reg A-frags, LDS W2) -----
// wave w owns rows m0+w*16..+15; thread (fr,ko) gates exactly its MFMA A-frag
// cols; row sum-sq closes with 2 shuffles. W2 staged ONCE into LDS (66 KB) and
// B-frags ds_read from there — no per-MFMA global latency, one barrier.
__global__ __launch_bounds__(256, 2) void k_gemm2g(const unsigned short* __restrict__ ybb,
                                                   const unsigned short* __restrict__ zb,
                                                   const float* __restrict__ gw,
                                                   const unsigned short* __restrict__ w2b,
                                                   const float* __restrict__ xin,
                                                   float* __restrict__ out) {
    __shared__ bf16 Ws[128 * 264];
    __shared__ float gwl[256];
    const int t = threadIdx.x;
    // stage W2: 128 rows x 256 cols bf16, 16B units, coalesced
    #pragma unroll
    for (int i = 0; i < 16; i++) {
        int f = i * 256 + t;
        int n = f >> 5, u = (f & 31) * 8;
        *(bf16x8*)&Ws[n * 264 + u] = *(const bf16x8*)(w2b + (size_t)n * DI + u);
    }
    gwl[t] = gw[t];
    const int wave = t >> 6, lane = t & 63;
    const int fr = lane & 15, ko = lane >> 4;
    const int m0 = blockIdx.x * 64 + wave * 16;
    const size_t rowo = (size_t)(m0 + fr) * DI;
    float ss = 0.f;
    bf16x8 gb[8];
    #pragma unroll
    for (int kk = 0; kk < 8; kk++) {
        int co = kk * 32 + ko * 8;
        bf16x8 yv = *(const bf16x8*)(ybb + rowo + co);
        bf16x8 zv = *(const bf16x8*)(zb + rowo + co);
        #pragma unroll
        for (int j = 0; j < 8; j++) {
            float z = (float)zv[j];
            float g = (float)yv[j] * (z / (1.f + expf(-z)));
            ss += g * g;
            gb[kk][j] = (bf16)g;
        }
    }
    ss += __shfl_xor(ss, 16);
    ss += __shfl_xor(ss, 32);
    const float rs = rsqrtf(ss * (1.0f / DI) + EPSF);
    __syncthreads();                       // Ws + gwl visible
    #pragma unroll
    for (int kk = 0; kk < 8; kk++) {
        int co = kk * 32 + ko * 8;
        #pragma unroll
        for (int j = 0; j < 8; j++)
            gb[kk][j] = (bf16)((float)gb[kk][j] * rs * gwl[co + j]);
    }
    f32x4 acc[8] = {};
    #pragma unroll
    for (int kk = 0; kk < 8; kk++) {
        #pragma unroll
        for (int nt = 0; nt < 8; nt++) {
            bf16x8 bfr = *(const bf16x8*)&Ws[(nt * 16 + fr) * 264 + kk * 32 + ko * 8];
            acc[nt] = __builtin_amdgcn_mfma_f32_16x16x32_bf16(gb[kk], bfr, acc[nt], 0, 0, 0);
        }
    }
    #pragma unroll
    for (int nt = 0; nt < 8; nt++) {
        int n = nt * 16 + fr;
        #pragma unroll
        for (int rr = 0; rr < 4; rr++) {
            int m = m0 + ko * 4 + rr;
            out[(size_t)m * DM + n] = xin[(size_t)m * DM + n] + acc[nt][rr];
        }
    }
}

extern "C" void kernel_launch(void* const* d_in, const int* in_sizes, int n_in,
                              void* d_out, int out_size, void* d_ws, size_t ws_size,
                              hipStream_t stream) {
    const float* x   = (const float*)d_in[0];
    const float* nw  = (const float*)d_in[1];
    const float* w1  = (const float*)d_in[2];
    const float* cw  = (const float*)d_in[3];
    const float* cb  = (const float*)d_in[4];
    const float* dtb = (const float*)d_in[5];
    const float* al  = (const float*)d_in[6];
    const float* Dw  = (const float*)d_in[7];
    const float* gw  = (const float*)d_in[8];
    const float* w2  = (const float*)d_in[9];
    float* out = (float*)d_out;

    float* ws = (float*)d_ws;
    float*  dAp = ws;                                   // 4096 fp32
    float*  dtf = dAp + NB * NH * NC;                   // NTOK*8 fp32
    unsigned short* hst = (unsigned short*)(dtf + (size_t)NTOK * NH); // 64*64*2048 bf16
    unsigned short* zb  = hst + (size_t)NB * NH * NC * 2048;          // NTOK*256 bf16
    unsigned short* xbc = zb + (size_t)NTOK * DI;                     // NTOK*384 bf16
    unsigned short* xcb = xbc + (size_t)NTOK * CDIM;                  // NTOK*384 bf16
    unsigned short* ybb = xcb + (size_t)NTOK * CDIM;                  // NTOK*256 bf16
    unsigned short* w1b = ybb + (size_t)NTOK * DI;                    // 648*128
    unsigned short* w2b = w1b + (size_t)DPROJ * DM;                   // 128*256
    // alias (lifetimes disjoint): xnb dead before ssd3 writes ybb
    unsigned short* xnb = ybb;

    k_cast<<<(DPROJ * DM + 255) / 256, 256, 0, stream>>>(w1, w1b, DPROJ * DM);
    k_cast<<<(DM * DI + 255) / 256, 256, 0, stream>>>(w2, w2b, DM * DI);
    k_rmsdt<<<NTOK / 4, 256, 0, stream>>>(x, nw, w1, dtb, xnb, dtf);
    k_gemm1<<<dim3(NTOK / 64, (DPROJ + 63) / 64), 256, 0, stream>>>(xnb, w1b, zb, xbc);
    k_conv<<<NTOK / 64, 384, 0, stream>>>(xbc, cw, cb, xcb);
    k_ssd1<<<NB * NH * (NC / 4), 256, 0, stream>>>(xcb, dtf, al, hst, dAp);
    k_ssm2<<<(NB * NH / 2) * 8, 256, 0, stream>>>(hst, dAp);
    k_ssd3<<<NB * NH * (NC / 4), 256, 0, stream>>>(xcb, dtf, al, hst, Dw, ybb);
    k_gemm2g<<<NTOK / 64, 256, 0, stream>>>(ybb, zb, gw, w2b, x, out);
}